// Round 6
// baseline (489.986 us; speedup 1.0000x reference)
//
#include <hip/hip_runtime.h>
#include <cstddef>

#define D_MODEL 1024
#define D_IN    2048
#define D_STATE 16
#define BATCH   4
#define SEQ     2048
#define NROWS   (BATCH * SEQ)   // 8192
#define NCHUNK  8
#define CHLEN   256             // SEQ / NCHUNK
#define MSTRIDE 1280            // floats per channel in mats (Pt,Gt,Wt,Qt,P256t)

typedef __attribute__((ext_vector_type(8))) short bf16x8;
typedef __attribute__((ext_vector_type(4))) float f32x4;
typedef unsigned short u16;

// Swizzle convention (shared by ALL producers and the GEMM readers):
// within each 64-elem k-window (8 chunks of 8 bf16 = 16B), logical chunk lc of
// row r is stored at physical chunk position lc ^ (r & 7).  global_load_lds
// copies linearly, so LDS inherits the swizzle; ds_read_b128 applies the same
// XOR => 16 consecutive rows hit 8 distinct 4-bank groups (2-way = free).

__device__ __forceinline__ void split_bf16(float f, short& hi, short& lo) {
    unsigned int u = __float_as_uint(f);
    hi = (short)(u >> 16);
    float fhi = __uint_as_float(u & 0xFFFF0000u);
    lo = (short)(__float_as_uint(f - fhi) >> 16);
}

__device__ __forceinline__ void gload16(const void* g, void* l) {
    __builtin_amdgcn_global_load_lds(
        (const __attribute__((address_space(1))) unsigned int*)g,
        (__attribute__((address_space(3))) unsigned int*)l, 16, 0, 0);
}

// ---------------- RMSNorm -> swizzled split-bf16 hi/lo ----------------
__global__ void rmsnorm_kernel(const float* __restrict__ x,
                               const float* __restrict__ w,
                               u16* __restrict__ hh, u16* __restrict__ hl) {
    const int row = blockIdx.x;
    const int c = threadIdx.x;              // chunk 0..127
    const float* xr = x + (size_t)row * D_MODEL;

    float4 va = reinterpret_cast<const float4*>(xr)[c * 2 + 0];
    float4 vb = reinterpret_cast<const float4*>(xr)[c * 2 + 1];
    float ss = va.x*va.x + va.y*va.y + va.z*va.z + va.w*va.w
             + vb.x*vb.x + vb.y*vb.y + vb.z*vb.z + vb.w*vb.w;
    #pragma unroll
    for (int off = 32; off > 0; off >>= 1) ss += __shfl_down(ss, off, 64);

    __shared__ float ws2[2];
    if ((threadIdx.x & 63) == 0) ws2[threadIdx.x >> 6] = ss;
    __syncthreads();
    const float tot = ws2[0] + ws2[1];
    const float scale = rsqrtf(tot * (1.0f / D_MODEL) + 1e-6f);

    float4 wa = reinterpret_cast<const float4*>(w)[c * 2 + 0];
    float4 wb = reinterpret_cast<const float4*>(w)[c * 2 + 1];
    float o[8] = { va.x*scale*wa.x, va.y*scale*wa.y, va.z*scale*wa.z, va.w*scale*wa.w,
                   vb.x*scale*wb.x, vb.y*scale*wb.y, vb.z*scale*wb.z, vb.w*scale*wb.w };
    bf16x8 vh, vl;
    #pragma unroll
    for (int e = 0; e < 8; ++e) { short h, l; split_bf16(o[e], h, l); vh[e] = h; vl[e] = l; }

    const size_t eb = (size_t)row * D_MODEL + (size_t)(c & ~7) * 8
                    + (size_t)((c & 7) ^ (row & 7)) * 8;
    *reinterpret_cast<bf16x8*>(&hh[eb]) = vh;
    *reinterpret_cast<bf16x8*>(&hl[eb]) = vl;
}

// ------------- transpose + split-cast (weights): in[R][C] f32 -> out[c][R] swizzled -------------
__global__ void transpose_cast_kernel(const float* __restrict__ in,
                                      u16* __restrict__ oh, u16* __restrict__ ol,
                                      int R, int C) {
    __shared__ float T[64][65];
    const int r0 = blockIdx.y * 64, c0 = blockIdx.x * 64;
    const int t = threadIdx.x;

    #pragma unroll
    for (int i = 0; i < 4; ++i) {
        const int r = (t >> 4) + i * 16;
        float4 v = *reinterpret_cast<const float4*>(
            &in[(size_t)(r0 + r) * C + c0 + (t & 15) * 4]);
        T[r][(t & 15) * 4 + 0] = v.x;
        T[r][(t & 15) * 4 + 1] = v.y;
        T[r][(t & 15) * 4 + 2] = v.z;
        T[r][(t & 15) * 4 + 3] = v.w;
    }
    __syncthreads();

    #pragma unroll
    for (int g = 0; g < 2; ++g) {
        const int idx = t + g * 256;   // 0..511
        const int c  = idx >> 3;       // out-row local 0..63
        const int rg = idx & 7;        // k-chunk within this 64-window
        bf16x8 vh, vl;
        #pragma unroll
        for (int e = 0; e < 8; ++e) {
            short h, l;
            split_bf16(T[rg * 8 + e][c], h, l);
            vh[e] = h; vl[e] = l;
        }
        const int orow = c0 + c;
        const size_t ob = (size_t)orow * R + r0 + (size_t)(rg ^ (orow & 7)) * 8;
        *reinterpret_cast<bf16x8*>(&oh[ob]) = vh;
        *reinterpret_cast<bf16x8*>(&ol[ob]) = vl;
    }
}

// ---------------- Unified split-bf16 GEMM, global_load_lds staged ----------------
template<int KTOT, int EPI>
__global__ __launch_bounds__(256, 2) void gemm_gll(
    const u16* __restrict__ Agh, const u16* __restrict__ Agl,
    const u16* __restrict__ Bgh, const u16* __restrict__ Bgl,
    const float* __restrict__ bias, const float* __restrict__ resid,
    float* __restrict__ outp) {
    __shared__ __align__(16) char lds[65536];

    const int t = threadIdx.x;
    const int wv = t >> 6, lane = t & 63;
    const int lr = lane & 15, kb = lane >> 4;
    const int wr = (wv >> 1) * 64;
    const int wc = (wv & 1) * 64;
    const int a_r0 = (EPI == 0 ? blockIdx.x : blockIdx.y) * 128;
    const int b_r0 = (EPI == 0 ? blockIdx.y : blockIdx.x) * 128;

    const u16* garr = (wv == 0) ? Agh : (wv == 1) ? Agl : (wv == 2) ? Bgh : Bgl;
    const int grow0 = (wv < 2) ? a_r0 : b_r0;
    char* lbase = lds + wv * 16384;
    const u16* gsrc = garr + (size_t)(grow0 + (lane >> 3)) * KTOT + (lane & 7) * 8;

    f32x4 acc[4][4];
    #pragma unroll
    for (int i = 0; i < 4; ++i)
        #pragma unroll
        for (int j = 0; j < 4; ++j) acc[i][j] = (f32x4)(0.f);

    for (int k0 = 0; k0 < KTOT; k0 += 64) {
        if (k0) __syncthreads();
        const u16* gk = gsrc + k0;
        #pragma unroll
        for (int sgi = 0; sgi < 16; ++sgi)
            gload16(gk + (size_t)sgi * 8 * KTOT, lbase + sgi * 1024);
        __syncthreads();

        #pragma unroll
        for (int ks = 0; ks < 2; ++ks) {
            bf16x8 afh[4], afl[4], bfh[4], bfl[4];
            #pragma unroll
            for (int i = 0; i < 4; ++i) {
                const int ra = wr + i * 16 + lr;
                const int oa = (ra << 7) + (((ks * 4 + kb) ^ (ra & 7)) << 4);
                afh[i] = *reinterpret_cast<const bf16x8*>(lds + oa);
                afl[i] = *reinterpret_cast<const bf16x8*>(lds + 16384 + oa);
                const int rb = wc + i * 16 + lr;
                const int ob = (rb << 7) + (((ks * 4 + kb) ^ (rb & 7)) << 4);
                bfh[i] = *reinterpret_cast<const bf16x8*>(lds + 32768 + ob);
                bfl[i] = *reinterpret_cast<const bf16x8*>(lds + 49152 + ob);
            }
            #pragma unroll
            for (int i = 0; i < 4; ++i)
                #pragma unroll
                for (int j = 0; j < 4; ++j) {
                    acc[i][j] = __builtin_amdgcn_mfma_f32_16x16x32_bf16(afh[i], bfh[j], acc[i][j], 0, 0, 0);
                    acc[i][j] = __builtin_amdgcn_mfma_f32_16x16x32_bf16(afh[i], bfl[j], acc[i][j], 0, 0, 0);
                    acc[i][j] = __builtin_amdgcn_mfma_f32_16x16x32_bf16(afl[i], bfh[j], acc[i][j], 0, 0, 0);
                }
        }
    }

    if (EPI == 0) {
        const int b = b_r0 >> 11;
        const int s_base = b_r0 & (SEQ - 1);
        #pragma unroll
        for (int i = 0; i < 4; ++i) {
            #pragma unroll
            for (int r = 0; r < 4; ++r) {
                const int d = a_r0 + wr + i * 16 + kb * 4 + r;
                const float bb = bias[d];
                float* dst = outp + (size_t)b * D_IN * SEQ + (size_t)d * SEQ + s_base;
                #pragma unroll
                for (int j = 0; j < 4; ++j)
                    dst[wc + j * 16 + lr] = acc[i][j][r] + bb;
            }
        }
    } else {
        #pragma unroll
        for (int i = 0; i < 4; ++i) {
            #pragma unroll
            for (int r = 0; r < 4; ++r) {
                const int row = a_r0 + wr + i * 16 + kb * 4 + r;
                #pragma unroll
                for (int j = 0; j < 4; ++j) {
                    const int col = b_r0 + wc + j * 16 + lr;
                    outp[(size_t)row * D_MODEL + col] =
                        acc[i][j][r] + bias[col] + resid[(size_t)row * D_MODEL + col];
                }
            }
        }
    }
}

// ---------------- Prep: per-channel scan matrices + A^256 ----------------
// mats[d][0..255]=Pt (A^16, [s][r]); [256..511]=Gt; [512..767]=Wt; [768..1023]=Qt;
// [1024..1279]=P256t (A^256, [s][r]).
__global__ void prep_kernel(const float* __restrict__ A,
                            const float* __restrict__ Bm,
                            const float* __restrict__ Cm,
                            float* __restrict__ mats) {
    const int d = blockIdx.x;
    const int t = threadIdx.x;
    const int r = t >> 4, sc = t & 15;

    __shared__ float Ash[16][17];
    __shared__ float Mcur[16][17];
    __shared__ float Bv[16], Cv[16], gs[16], cd[16];

    Ash[r][sc] = A[(size_t)d * 256 + r * 16 + sc];
    if (t < 16) { Bv[t] = Bm[d * 16 + t]; Cv[t] = Cm[d * 16 + t]; }
    Mcur[r][sc] = (r == sc) ? 1.f : 0.f;
    __syncthreads();

    float* md = mats + (size_t)d * MSTRIDE;

    for (int m = 0; m <= 16; ++m) {
        float g = 0.f, wv = 0.f, acc = 0.f;
        if (m <= 15 && t < 16) {
            #pragma unroll
            for (int rr = 0; rr < 16; ++rr) g = fmaf(Bv[rr], Mcur[rr][t], g);
        }
        if (m >= 1 && sc == 0) {
            #pragma unroll
            for (int ss = 0; ss < 16; ++ss) wv = fmaf(Mcur[r][ss], Cv[ss], wv);
        }
        if (m == 16) md[0 + sc * 16 + r] = Mcur[r][sc];
        if (m < 16) {
            #pragma unroll
            for (int k = 0; k < 16; ++k) acc = fmaf(Mcur[r][k], Ash[k][sc], acc);
        }
        if (m <= 15 && t < 16) { md[256 + t * 16 + (15 - m)] = g; gs[t] = g; }
        if (m >= 1 && sc == 0) md[512 + (m - 1) * 16 + r] = wv;
        __syncthreads();
        if (m <= 15 && t == 0) {
            float c = 0.f;
            #pragma unroll
            for (int ss = 0; ss < 16; ++ss) c = fmaf(gs[ss], Cv[ss], c);
            cd[m] = c;
        }
        if (m < 16) Mcur[r][sc] = acc;
        __syncthreads();
    }
    md[768 + r * 16 + sc] = (sc <= r) ? cd[r - sc] : 0.f;

    // Square A^16 four times -> A^256
    #pragma unroll
    for (int q = 0; q < 4; ++q) {
        float a2 = 0.f;
        #pragma unroll
        for (int k = 0; k < 16; ++k) a2 = fmaf(Mcur[r][k], Mcur[k][sc], a2);
        __syncthreads();
        Mcur[r][sc] = a2;
        __syncthreads();
    }
    md[1024 + sc * 16 + r] = Mcur[r][sc];
}

// ---------------- Phase 1: per-(d,chunk) local state (no y, no barriers) ----------------
// wave = (d, c); lane = b*16+s. Writes vbuf[(d*8+c)*64 + lane].
__global__ __launch_bounds__(256) void scan_p1(
    const float* __restrict__ u,
    const float* __restrict__ conv_w, const float* __restrict__ conv_b,
    const float* __restrict__ mats, float* __restrict__ vbuf) {
    const int wid = blockIdx.x * 4 + (threadIdx.x >> 6);   // 0..16383
    const int d = wid >> 3, c = wid & 7;
    const int lane = threadIdx.x & 63;
    const int s = lane & 15, b = lane >> 4, base = lane & 48;

    const float* md = mats + (size_t)d * MSTRIDE;
    float Pt[16], Gt[16];
    #pragma unroll
    for (int q = 0; q < 4; ++q) {
        float4 v;
        v = reinterpret_cast<const float4*>(md + 0   + s * 16)[q];
        Pt[4*q+0]=v.x; Pt[4*q+1]=v.y; Pt[4*q+2]=v.z; Pt[4*q+3]=v.w;
        v = reinterpret_cast<const float4*>(md + 256 + s * 16)[q];
        Gt[4*q+0]=v.x; Gt[4*q+1]=v.y; Gt[4*q+2]=v.z; Gt[4*q+3]=v.w;
    }
    const float w0 = conv_w[d * 4 + 0];
    const float w1 = conv_w[d * 4 + 1];
    const float w2 = conv_w[d * 4 + 2];
    const float w3 = conv_w[d * 4 + 3];
    const float cb = conv_b[d];

    const float* up = u + (size_t)b * D_IN * SEQ + (size_t)d * SEQ;
    const int t0 = c * CHLEN;
    float c1 = 0.f, c2 = 0.f, c3 = 0.f;
    if (t0 > 0) { c1 = up[t0 - 1]; c2 = up[t0 - 2]; c3 = up[t0 - 3]; }

    float hc = 0.f;
    for (int m = 0; m < CHLEN / 16; ++m) {
        const float x = up[t0 + 16 * m + s];

        float xm1 = __shfl(x, (lane - 1) & 63, 64);
        float xm2 = __shfl(x, (lane - 2) & 63, 64);
        float xm3 = __shfl(x, (lane - 3) & 63, 64);
        if (s == 0) xm1 = c1;
        if (s <= 1) xm2 = (s == 1) ? c1 : c2;
        if (s <= 2) xm3 = (s == 2) ? c1 : ((s == 1) ? c2 : c3);
        const float uval = fmaf(w3, x, fmaf(w2, xm1, fmaf(w1, xm2, fmaf(w0, xm3, cb))));

        const float n1 = __shfl(x, base + 15, 64);
        const float n2 = __shfl(x, base + 14, 64);
        const float n3 = __shfl(x, base + 13, 64);

        float hnA = 0.f, hnB = 0.f;
        #pragma unroll
        for (int rq = 0; rq < 8; ++rq) {
            hnA = fmaf(__shfl(hc, base + 2 * rq + 0, 64), Pt[2 * rq + 0], hnA);
            hnB = fmaf(__shfl(hc, base + 2 * rq + 1, 64), Pt[2 * rq + 1], hnB);
        }
        #pragma unroll
        for (int iq = 0; iq < 8; ++iq) {
            hnA = fmaf(__shfl(uval, base + 2 * iq + 0, 64), Gt[2 * iq + 0], hnA);
            hnB = fmaf(__shfl(uval, base + 2 * iq + 1, 64), Gt[2 * iq + 1], hnB);
        }
        hc = hnA + hnB;
        c1 = n1; c2 = n2; c3 = n3;
    }
    vbuf[(size_t)wid * 64 + lane] = hc;
}

// ---------------- Phase 2: sequential chunk combine (A^256) ----------------
// One wave per d. hbuf[(d*8+c)*64+lane] = state at START of chunk c.
__global__ __launch_bounds__(256) void scan_p2(
    const float* __restrict__ mats,
    const float* __restrict__ vbuf, float* __restrict__ hbuf) {
    const int d = blockIdx.x * 4 + (threadIdx.x >> 6);
    const int lane = threadIdx.x & 63;
    const int s = lane & 15, base = lane & 48;

    const float* md = mats + (size_t)d * MSTRIDE + 1024;
    float Pt[16];
    #pragma unroll
    for (int q = 0; q < 4; ++q) {
        float4 v = reinterpret_cast<const float4*>(md + s * 16)[q];
        Pt[4*q+0]=v.x; Pt[4*q+1]=v.y; Pt[4*q+2]=v.z; Pt[4*q+3]=v.w;
    }

    float hc = 0.f;
    for (int c = 0; c < NCHUNK; ++c) {
        hbuf[((size_t)d * 8 + c) * 64 + lane] = hc;
        const float v = vbuf[((size_t)d * 8 + c) * 64 + lane];
        float hnA = 0.f, hnB = 0.f;
        #pragma unroll
        for (int rq = 0; rq < 8; ++rq) {
            hnA = fmaf(__shfl(hc, base + 2 * rq + 0, 64), Pt[2 * rq + 0], hnA);
            hnB = fmaf(__shfl(hc, base + 2 * rq + 1, 64), Pt[2 * rq + 1], hnB);
        }
        hc = hnA + hnB + v;
    }
}

// ---------------- Phase 3: full scan per (d-group, chunk), y output ----------------
// grid(256, 8): blockIdx.x = 8-channel group (same swizzle roles as before),
// blockIdx.y = chunk. 8 waves = 8 channels.
__global__ __launch_bounds__(512) void scan_p3(
    const float* __restrict__ u,
    const float* __restrict__ conv_w, const float* __restrict__ conv_b,
    const float* __restrict__ mats, const float* __restrict__ hbuf,
    u16* __restrict__ y2h, u16* __restrict__ y2l) {
    const int wv = threadIdx.x >> 6;
    const int lane = threadIdx.x & 63;
    const int d = blockIdx.x * 8 + wv;
    const int ch = blockIdx.y;
    const int s = lane & 15, b = lane >> 4, base = lane & 48;

    __shared__ float Yt[2][8][64];

    const float* md = mats + (size_t)d * MSTRIDE;
    float Pt[16], Gt[16], Wt[16], Qt[16];
    #pragma unroll
    for (int q = 0; q < 4; ++q) {
        float4 v;
        v = reinterpret_cast<const float4*>(md + 0   + s * 16)[q];
        Pt[4*q+0]=v.x; Pt[4*q+1]=v.y; Pt[4*q+2]=v.z; Pt[4*q+3]=v.w;
        v = reinterpret_cast<const float4*>(md + 256 + s * 16)[q];
        Gt[4*q+0]=v.x; Gt[4*q+1]=v.y; Gt[4*q+2]=v.z; Gt[4*q+3]=v.w;
        v = reinterpret_cast<const float4*>(md + 512 + s * 16)[q];
        Wt[4*q+0]=v.x; Wt[4*q+1]=v.y; Wt[4*q+2]=v.z; Wt[4*q+3]=v.w;
        v = reinterpret_cast<const float4*>(md + 768 + s * 16)[q];
        Qt[4*q+0]=v.x; Qt[4*q+1]=v.y; Qt[4*q+2]=v.z; Qt[4*q+3]=v.w;
    }
    const float w0 = conv_w[d * 4 + 0];
    const float w1 = conv_w[d * 4 + 1];
    const float w2 = conv_w[d * 4 + 2];
    const float w3 = conv_w[d * 4 + 3];
    const float cb = conv_b[d];

    const float* up = u + (size_t)b * D_IN * SEQ + (size_t)d * SEQ;
    const int t0 = ch * CHLEN;
    float c1 = 0.f, c2 = 0.f, c3 = 0.f;
    if (t0 > 0) { c1 = up[t0 - 1]; c2 = up[t0 - 2]; c3 = up[t0 - 3]; }

    float hc = hbuf[((size_t)d * 8 + ch) * 64 + lane];

    const int w64 = (blockIdx.x * 8) & ~63;
    const int lc  = blockIdx.x & 7;

    for (int m = 0; m < CHLEN / 16; ++m) {
        const float x = up[t0 + 16 * m + s];

        float xm1 = __shfl(x, (lane - 1) & 63, 64);
        float xm2 = __shfl(x, (lane - 2) & 63, 64);
        float xm3 = __shfl(x, (lane - 3) & 63, 64);
        if (s == 0) xm1 = c1;
        if (s <= 1) xm2 = (s == 1) ? c1 : c2;
        if (s <= 2) xm3 = (s == 2) ? c1 : ((s == 1) ? c2 : c3);
        const float uval = fmaf(w3, x, fmaf(w2, xm1, fmaf(w1, xm2, fmaf(w0, xm3, cb))));

        const float n1 = __shfl(x, base + 15, 64);
        const float n2 = __shfl(x, base + 14, 64);
        const float n3 = __shfl(x, base + 13, 64);

        float hnA = 0.f, hnB = 0.f, yvA = 0.f, yvB = 0.f;
        #pragma unroll
        for (int rq = 0; rq < 8; ++rq) {
            const float h0 = __shfl(hc, base + 2 * rq + 0, 64);
            const float h1 = __shfl(hc, base + 2 * rq + 1, 64);
            hnA = fmaf(h0, Pt[2 * rq + 0], hnA);
            hnB = fmaf(h1, Pt[2 * rq + 1], hnB);
            yvA = fmaf(h0, Wt[2 * rq + 0], yvA);
            yvB = fmaf(h1, Wt[2 * rq + 1], yvB);
        }
        #pragma unroll
        for (int iq = 0; iq < 8; ++iq) {
            const float u0 = __shfl(uval, base + 2 * iq + 0, 64);
            const float u1 = __shfl(uval, base + 2 * iq + 1, 64);
            hnA = fmaf(u0, Gt[2 * iq + 0], hnA);
            hnB = fmaf(u1, Gt[2 * iq + 1], hnB);
            yvA = fmaf(u0, Qt[2 * iq + 0], yvA);
            yvB = fmaf(u1, Qt[2 * iq + 1], yvB);
        }
        hc = hnA + hnB;
        c1 = n1; c2 = n2; c3 = n3;

        Yt[m & 1][wv][lane] = yvA + yvB;
        __syncthreads();

        if (lane < 16) {
            const int mm = wv * 8 + (lane & 7);
            const int half = lane >> 3;
            const int bb = mm >> 4, ssg = mm & 15;
            const size_t orow = (size_t)bb * SEQ + t0 + 16 * m + ssg;
            short4 vh, vl;
            split_bf16(Yt[m & 1][half * 4 + 0][mm], vh.x, vl.x);
            split_bf16(Yt[m & 1][half * 4 + 1][mm], vh.y, vl.y);
            split_bf16(Yt[m & 1][half * 4 + 2][mm], vh.z, vl.z);
            split_bf16(Yt[m & 1][half * 4 + 3][mm], vh.w, vl.w);
            const size_t eb = orow * D_IN + w64
                            + (size_t)((lc ^ (int)(orow & 7)) << 3) + half * 4;
            *reinterpret_cast<short4*>(&y2h[eb]) = vh;
            *reinterpret_cast<short4*>(&y2l[eb]) = vl;
        }
    }
}

extern "C" void kernel_launch(void* const* d_in, const int* in_sizes, int n_in,
                              void* d_out, int out_size, void* d_ws, size_t ws_size,
                              hipStream_t stream) {
    const float* x      = (const float*)d_in[0];
    const float* norm_w = (const float*)d_in[1];
    const float* Win    = (const float*)d_in[2];
    const float* b_in   = (const float*)d_in[3];
    const float* conv_w = (const float*)d_in[4];
    const float* conv_b = (const float*)d_in[5];
    const float* A      = (const float*)d_in[6];
    const float* Bm     = (const float*)d_in[7];
    const float* Cm     = (const float*)d_in[8];
    const float* Wout   = (const float*)d_in[9];
    const float* b_out  = (const float*)d_in[10];
    float* out = (float*)d_out;

    // ws (128MB), phase-overlapped:
    //   [0,64M):  u0T fp32 (gemm1 out; scan p1/p3 in) -> later Woth@[0,4M), Wotl@[4,8M)
    //   [64,128M): Wth@[64,68M), Wtl@[68,72M)         -> later y2h@[64,96M), y2l@[96,128M)
    // d_out (32MB): hh/hl (rmsnorm->gemm1) -> mats[0,10M)+vbuf[11,15M)+hbuf[15,19M)
    //               -> final output (gemm2)
    char* W = (char*)d_ws;
    float* u0T = (float*)W;
    u16* Wth  = (u16*)(W + ((size_t)64 << 20));
    u16* Wtl  = (u16*)(W + ((size_t)68 << 20));
    u16* y2h  = (u16*)(W + ((size_t)64 << 20));
    u16* y2l  = (u16*)(W + ((size_t)96 << 20));
    u16* Woth = (u16*)W;
    u16* Wotl = (u16*)(W + ((size_t)4 << 20));
    u16* hh = (u16*)d_out;
    u16* hl = hh + (size_t)NROWS * D_MODEL;
    float* mats = (float*)d_out;
    float* vbuf = (float*)((char*)d_out + ((size_t)11 << 20));
    float* hbuf = (float*)((char*)d_out + ((size_t)15 << 20));

    // 1) Win -> Win^T split/swizzled
    {
        dim3 g(D_IN / 64, D_MODEL / 64);
        transpose_cast_kernel<<<g, 256, 0, stream>>>(Win, Wth, Wtl, D_MODEL, D_IN);
    }
    // 2) RMSNorm -> h split/swizzled (d_out)
    rmsnorm_kernel<<<NROWS, 128, 0, stream>>>(x, norm_w, hh, hl);
    // 3) u0T = h @ Win + b_in
    {
        dim3 grid(D_IN / 128, NROWS / 128);
        gemm_gll<D_MODEL, 0><<<grid, 256, 0, stream>>>(Wth, Wtl, hh, hl, b_in, nullptr, u0T);
    }
    // 4) scan matrices (hh/hl dead)
    prep_kernel<<<D_IN, 256, 0, stream>>>(A, Bm, Cm, mats);
    // 5) chunked scan: local states -> combine -> full scan with y output
    scan_p1<<<D_IN * NCHUNK / 4, 256, 0, stream>>>(u0T, conv_w, conv_b, mats, vbuf);
    scan_p2<<<D_IN / 4, 256, 0, stream>>>(mats, vbuf, hbuf);
    {
        dim3 g(D_IN / 8, NCHUNK);
        scan_p3<<<g, 512, 0, stream>>>(u0T, conv_w, conv_b, mats, hbuf, y2h, y2l);
    }
    // 6) Wout -> Wout^T split/swizzled (u0T dead)
    {
        dim3 g(D_MODEL / 64, D_IN / 64);
        transpose_cast_kernel<<<g, 256, 0, stream>>>(Wout, Woth, Wotl, D_IN, D_MODEL);
    }
    // 7) out = y @ Wout + b_out + x (mats/vbuf/hbuf dead)
    {
        dim3 grid(D_MODEL / 128, NROWS / 128);
        gemm_gll<D_IN, 1><<<grid, 256, 0, stream>>>(y2h, y2l, Woth, Wotl, b_out, x, out);
    }
}

// Round 7
// 306.110 us; speedup vs baseline: 1.6007x; 1.6007x over previous
//
#include <hip/hip_runtime.h>
#include <cstddef>

#define D_MODEL 1024
#define D_IN    2048
#define D_STATE 16
#define BATCH   4
#define SEQ     2048
#define NROWS   (BATCH * SEQ)   // 8192

typedef __attribute__((ext_vector_type(8))) short bf16x8;
typedef __attribute__((ext_vector_type(4))) float f32x4;
typedef unsigned short u16;

// Swizzle convention (shared by ALL producers and the GEMM readers):
// within each 64-elem k-window (8 chunks of 8 bf16 = 16B), logical chunk lc of
// row r is stored at physical chunk position lc ^ (r & 7).

__device__ __forceinline__ void split_bf16(float f, short& hi, short& lo) {
    unsigned int u = __float_as_uint(f);
    hi = (short)(u >> 16);
    float fhi = __uint_as_float(u & 0xFFFF0000u);
    lo = (short)(__float_as_uint(f - fhi) >> 16);
}

__device__ __forceinline__ void gload16(const void* g, void* l) {
    __builtin_amdgcn_global_load_lds(
        (const __attribute__((address_space(1))) unsigned int*)g,
        (__attribute__((address_space(3))) unsigned int*)l, 16, 0, 0);
}

// DPP lane ops on the VALU pipe (no DS traffic). Rows = 16 lanes = our (b) groups.
// 0x150+N = row_newbcast:N (bcast lane N of each row), 0x110+N = row_shr:N.
template<int CTRL>
__device__ __forceinline__ float dpp_mov(float v) {
    return __uint_as_float((unsigned)__builtin_amdgcn_update_dpp(
        0, (int)__float_as_uint(v), CTRL, 0xF, 0xF, false));
}

// ---------------- RMSNorm -> swizzled split-bf16 hi/lo ----------------
__global__ void rmsnorm_kernel(const float* __restrict__ x,
                               const float* __restrict__ w,
                               u16* __restrict__ hh, u16* __restrict__ hl) {
    const int row = blockIdx.x;
    const int c = threadIdx.x;              // chunk 0..127
    const float* xr = x + (size_t)row * D_MODEL;

    float4 va = reinterpret_cast<const float4*>(xr)[c * 2 + 0];
    float4 vb = reinterpret_cast<const float4*>(xr)[c * 2 + 1];
    float ss = va.x*va.x + va.y*va.y + va.z*va.z + va.w*va.w
             + vb.x*vb.x + vb.y*vb.y + vb.z*vb.z + vb.w*vb.w;
    #pragma unroll
    for (int off = 32; off > 0; off >>= 1) ss += __shfl_down(ss, off, 64);

    __shared__ float ws2[2];
    if ((threadIdx.x & 63) == 0) ws2[threadIdx.x >> 6] = ss;
    __syncthreads();
    const float tot = ws2[0] + ws2[1];
    const float scale = rsqrtf(tot * (1.0f / D_MODEL) + 1e-6f);

    float4 wa = reinterpret_cast<const float4*>(w)[c * 2 + 0];
    float4 wb = reinterpret_cast<const float4*>(w)[c * 2 + 1];
    float o[8] = { va.x*scale*wa.x, va.y*scale*wa.y, va.z*scale*wa.z, va.w*scale*wa.w,
                   vb.x*scale*wb.x, vb.y*scale*wb.y, vb.z*scale*wb.z, vb.w*scale*wb.w };
    bf16x8 vh, vl;
    #pragma unroll
    for (int e = 0; e < 8; ++e) { short h, l; split_bf16(o[e], h, l); vh[e] = h; vl[e] = l; }

    const size_t eb = (size_t)row * D_MODEL + (size_t)(c & ~7) * 8
                    + (size_t)((c & 7) ^ (row & 7)) * 8;
    *reinterpret_cast<bf16x8*>(&hh[eb]) = vh;
    *reinterpret_cast<bf16x8*>(&hl[eb]) = vl;
}

// ------------- transpose + split-cast (weights): in[R][C] f32 -> out[c][R] swizzled -------------
__global__ void transpose_cast_kernel(const float* __restrict__ in,
                                      u16* __restrict__ oh, u16* __restrict__ ol,
                                      int R, int C) {
    __shared__ float T[64][65];
    const int r0 = blockIdx.y * 64, c0 = blockIdx.x * 64;
    const int t = threadIdx.x;

    #pragma unroll
    for (int i = 0; i < 4; ++i) {
        const int r = (t >> 4) + i * 16;
        float4 v = *reinterpret_cast<const float4*>(
            &in[(size_t)(r0 + r) * C + c0 + (t & 15) * 4]);
        T[r][(t & 15) * 4 + 0] = v.x;
        T[r][(t & 15) * 4 + 1] = v.y;
        T[r][(t & 15) * 4 + 2] = v.z;
        T[r][(t & 15) * 4 + 3] = v.w;
    }
    __syncthreads();

    #pragma unroll
    for (int g = 0; g < 2; ++g) {
        const int idx = t + g * 256;   // 0..511
        const int c  = idx >> 3;       // out-row local 0..63
        const int rg = idx & 7;        // k-chunk within this 64-window
        bf16x8 vh, vl;
        #pragma unroll
        for (int e = 0; e < 8; ++e) {
            short h, l;
            split_bf16(T[rg * 8 + e][c], h, l);
            vh[e] = h; vl[e] = l;
        }
        const int orow = c0 + c;
        const size_t ob = (size_t)orow * R + r0 + (size_t)(rg ^ (orow & 7)) * 8;
        *reinterpret_cast<bf16x8*>(&oh[ob]) = vh;
        *reinterpret_cast<bf16x8*>(&ol[ob]) = vl;
    }
}

// ---------------- Unified split-bf16 GEMM, global_load_lds staged ----------------
template<int KTOT, int EPI>
__global__ __launch_bounds__(256, 2) void gemm_gll(
    const u16* __restrict__ Agh, const u16* __restrict__ Agl,
    const u16* __restrict__ Bgh, const u16* __restrict__ Bgl,
    const float* __restrict__ bias, const float* __restrict__ resid,
    float* __restrict__ outp) {
    __shared__ __align__(16) char lds[65536];

    const int t = threadIdx.x;
    const int wv = t >> 6, lane = t & 63;
    const int lr = lane & 15, kb = lane >> 4;
    const int wr = (wv >> 1) * 64;
    const int wc = (wv & 1) * 64;
    const int a_r0 = (EPI == 0 ? blockIdx.x : blockIdx.y) * 128;
    const int b_r0 = (EPI == 0 ? blockIdx.y : blockIdx.x) * 128;

    const u16* garr = (wv == 0) ? Agh : (wv == 1) ? Agl : (wv == 2) ? Bgh : Bgl;
    const int grow0 = (wv < 2) ? a_r0 : b_r0;
    char* lbase = lds + wv * 16384;
    const u16* gsrc = garr + (size_t)(grow0 + (lane >> 3)) * KTOT + (lane & 7) * 8;

    f32x4 acc[4][4];
    #pragma unroll
    for (int i = 0; i < 4; ++i)
        #pragma unroll
        for (int j = 0; j < 4; ++j) acc[i][j] = (f32x4)(0.f);

    for (int k0 = 0; k0 < KTOT; k0 += 64) {
        if (k0) __syncthreads();
        const u16* gk = gsrc + k0;
        #pragma unroll
        for (int sgi = 0; sgi < 16; ++sgi)
            gload16(gk + (size_t)sgi * 8 * KTOT, lbase + sgi * 1024);
        __syncthreads();

        #pragma unroll
        for (int ks = 0; ks < 2; ++ks) {
            bf16x8 afh[4], afl[4], bfh[4], bfl[4];
            #pragma unroll
            for (int i = 0; i < 4; ++i) {
                const int ra = wr + i * 16 + lr;
                const int oa = (ra << 7) + (((ks * 4 + kb) ^ (ra & 7)) << 4);
                afh[i] = *reinterpret_cast<const bf16x8*>(lds + oa);
                afl[i] = *reinterpret_cast<const bf16x8*>(lds + 16384 + oa);
                const int rb = wc + i * 16 + lr;
                const int ob = (rb << 7) + (((ks * 4 + kb) ^ (rb & 7)) << 4);
                bfh[i] = *reinterpret_cast<const bf16x8*>(lds + 32768 + ob);
                bfl[i] = *reinterpret_cast<const bf16x8*>(lds + 49152 + ob);
            }
            #pragma unroll
            for (int i = 0; i < 4; ++i)
                #pragma unroll
                for (int j = 0; j < 4; ++j) {
                    acc[i][j] = __builtin_amdgcn_mfma_f32_16x16x32_bf16(afh[i], bfh[j], acc[i][j], 0, 0, 0);
                    acc[i][j] = __builtin_amdgcn_mfma_f32_16x16x32_bf16(afh[i], bfl[j], acc[i][j], 0, 0, 0);
                    acc[i][j] = __builtin_amdgcn_mfma_f32_16x16x32_bf16(afl[i], bfh[j], acc[i][j], 0, 0, 0);
                }
        }
    }

    if (EPI == 0) {
        const int b = b_r0 >> 11;
        const int s_base = b_r0 & (SEQ - 1);
        #pragma unroll
        for (int i = 0; i < 4; ++i) {
            #pragma unroll
            for (int r = 0; r < 4; ++r) {
                const int d = a_r0 + wr + i * 16 + kb * 4 + r;
                const float bb = bias[d];
                float* dst = outp + (size_t)b * D_IN * SEQ + (size_t)d * SEQ + s_base;
                #pragma unroll
                for (int j = 0; j < 4; ++j)
                    dst[wc + j * 16 + lr] = acc[i][j][r] + bb;
            }
        }
    } else {
        #pragma unroll
        for (int i = 0; i < 4; ++i) {
            #pragma unroll
            for (int r = 0; r < 4; ++r) {
                const int row = a_r0 + wr + i * 16 + kb * 4 + r;
                #pragma unroll
                for (int j = 0; j < 4; ++j) {
                    const int col = b_r0 + wc + j * 16 + lr;
                    outp[(size_t)row * D_MODEL + col] =
                        acc[i][j][r] + bias[col] + resid[(size_t)row * D_MODEL + col];
                }
            }
        }
    }
}

// ---------------- Prep: per-channel scan matrices ----------------
__global__ void prep_kernel(const float* __restrict__ A,
                            const float* __restrict__ Bm,
                            const float* __restrict__ Cm,
                            float* __restrict__ mats) {
    const int d = blockIdx.x;
    const int t = threadIdx.x;
    const int r = t >> 4, sc = t & 15;

    __shared__ float Ash[16][17];
    __shared__ float Mcur[16][17];
    __shared__ float Bv[16], Cv[16], gs[16], cd[16];

    Ash[r][sc] = A[(size_t)d * 256 + r * 16 + sc];
    if (t < 16) { Bv[t] = Bm[d * 16 + t]; Cv[t] = Cm[d * 16 + t]; }
    Mcur[r][sc] = (r == sc) ? 1.f : 0.f;
    __syncthreads();

    float* md = mats + (size_t)d * 1024;

    for (int m = 0; m <= 16; ++m) {
        float g = 0.f, wv = 0.f, acc = 0.f;
        if (m <= 15 && t < 16) {
            #pragma unroll
            for (int rr = 0; rr < 16; ++rr) g = fmaf(Bv[rr], Mcur[rr][t], g);
        }
        if (m >= 1 && sc == 0) {
            #pragma unroll
            for (int ss = 0; ss < 16; ++ss) wv = fmaf(Mcur[r][ss], Cv[ss], wv);
        }
        if (m == 16) md[0 + sc * 16 + r] = Mcur[r][sc];
        if (m < 16) {
            #pragma unroll
            for (int k = 0; k < 16; ++k) acc = fmaf(Mcur[r][k], Ash[k][sc], acc);
        }
        if (m <= 15 && t < 16) { md[256 + t * 16 + (15 - m)] = g; gs[t] = g; }
        if (m >= 1 && sc == 0) md[512 + (m - 1) * 16 + r] = wv;
        __syncthreads();
        if (m <= 15 && t == 0) {
            float c = 0.f;
            #pragma unroll
            for (int ss = 0; ss < 16; ++ss) c = fmaf(gs[ss], Cv[ss], c);
            cd[m] = c;
        }
        if (m < 16) Mcur[r][sc] = acc;
        __syncthreads();
    }
    md[768 + r * 16 + sc] = (sc <= r) ? cd[r - sc] : 0.f;
}

// ------- Fused conv + scan (DPP cross-lane, no DS), 16 t per macro-step; 8 waves/block. -------
// Output: y split-bf16, TRANSPOSED [m=(b,s)][k=d] with baked swizzle (gemm2 A-operand).
__global__ __launch_bounds__(512) void scan8_dpp(
    const float* __restrict__ u,            // u0T [b][d][s] fp32
    const float* __restrict__ conv_w, const float* __restrict__ conv_b,
    const float* __restrict__ mats,
    u16* __restrict__ y2h, u16* __restrict__ y2l) {
    const int wv = threadIdx.x >> 6;        // 0..7
    const int lane = threadIdx.x & 63;
    const int d = blockIdx.x * 8 + wv;
    const int s = lane & 15;
    const int b = lane >> 4;

    __shared__ float Yt[8][8][64];          // [mi][d-slot][(b,s)]

    const float* md = mats + (size_t)d * 1024;
    float Pt[16], Gt[16], Wt[16], Qt[16];
    #pragma unroll
    for (int q = 0; q < 4; ++q) {
        float4 v;
        v = reinterpret_cast<const float4*>(md + 0   + s * 16)[q];
        Pt[4*q+0]=v.x; Pt[4*q+1]=v.y; Pt[4*q+2]=v.z; Pt[4*q+3]=v.w;
        v = reinterpret_cast<const float4*>(md + 256 + s * 16)[q];
        Gt[4*q+0]=v.x; Gt[4*q+1]=v.y; Gt[4*q+2]=v.z; Gt[4*q+3]=v.w;
        v = reinterpret_cast<const float4*>(md + 512 + s * 16)[q];
        Wt[4*q+0]=v.x; Wt[4*q+1]=v.y; Wt[4*q+2]=v.z; Wt[4*q+3]=v.w;
        v = reinterpret_cast<const float4*>(md + 768 + s * 16)[q];
        Qt[4*q+0]=v.x; Qt[4*q+1]=v.y; Qt[4*q+2]=v.z; Qt[4*q+3]=v.w;
    }

    const float w0 = conv_w[d * 4 + 0];
    const float w1 = conv_w[d * 4 + 1];
    const float w2 = conv_w[d * 4 + 2];
    const float w3 = conv_w[d * 4 + 3];
    const float cb = conv_b[d];

    float hc = 0.f;
    float c1 = 0.f, c2 = 0.f, c3 = 0.f;

    const float* up = u + (size_t)b * D_IN * SEQ + (size_t)d * SEQ;
    const int w64 = (blockIdx.x * 8) & ~63;   // k-window base (elems)
    const int lc  = blockIdx.x & 7;           // logical chunk within window

    float x = up[s];                          // prefetched for m=0

    for (int m = 0; m < SEQ / 16; ++m) {
        const float xn = (m + 1 < SEQ / 16) ? up[16 * (m + 1) + s] : 0.f;

        // conv window via DPP row_shr + carries (rows = 16-lane b-groups)
        float xm1 = dpp_mov<0x111>(x);
        float xm2 = dpp_mov<0x112>(x);
        float xm3 = dpp_mov<0x113>(x);
        if (s == 0) xm1 = c1;
        if (s <= 1) xm2 = (s == 1) ? c1 : c2;
        if (s <= 2) xm3 = (s == 2) ? c1 : ((s == 1) ? c2 : c3);
        const float uval = fmaf(w3, x, fmaf(w2, xm1, fmaf(w1, xm2, fmaf(w0, xm3, cb))));

        const float n1 = dpp_mov<0x15F>(x);   // row_newbcast:15
        const float n2 = dpp_mov<0x15E>(x);
        const float n3 = dpp_mov<0x15D>(x);

        float hnA = 0.f, hnB = 0.f, yvA = 0.f, yvB = 0.f;
#define RQ(k) { \
        const float h0 = dpp_mov<0x150 + 2*(k)>(hc); \
        const float h1 = dpp_mov<0x151 + 2*(k)>(hc); \
        hnA = fmaf(h0, Pt[2*(k)+0], hnA); hnB = fmaf(h1, Pt[2*(k)+1], hnB); \
        yvA = fmaf(h0, Wt[2*(k)+0], yvA); yvB = fmaf(h1, Wt[2*(k)+1], yvB); }
        RQ(0) RQ(1) RQ(2) RQ(3) RQ(4) RQ(5) RQ(6) RQ(7)
#undef RQ
#define IQ(k) { \
        const float u0 = dpp_mov<0x150 + 2*(k)>(uval); \
        const float u1 = dpp_mov<0x151 + 2*(k)>(uval); \
        hnA = fmaf(u0, Gt[2*(k)+0], hnA); hnB = fmaf(u1, Gt[2*(k)+1], hnB); \
        yvA = fmaf(u0, Qt[2*(k)+0], yvA); yvB = fmaf(u1, Qt[2*(k)+1], yvB); }
        IQ(0) IQ(1) IQ(2) IQ(3) IQ(4) IQ(5) IQ(6) IQ(7)
#undef IQ
        hc = hnA + hnB;
        c1 = n1; c2 = n2; c3 = n3;
        x = xn;

        Yt[m & 7][wv][lane] = yvA + yvB;

        if ((m & 7) == 7) {
            __syncthreads();
            // write phase: 1024 (mi, mm, half) units, 2 per thread
            const int tbase = 16 * (m - 7);
            #pragma unroll
            for (int p = 0; p < 2; ++p) {
                const int idx = threadIdx.x + p * 512;   // 0..1023
                const int mi = idx >> 7;                 // 0..7
                const int rem = idx & 127;
                const int mm = rem >> 1;                 // 0..63 = (b',s')
                const int half = rem & 1;                // d-sub [half*4, half*4+4)
                const int bb = mm >> 4, ssg = mm & 15;
                const size_t orow = (size_t)bb * SEQ + tbase + 16 * mi + ssg;
                short4 vh, vl;
                split_bf16(Yt[mi][half * 4 + 0][mm], vh.x, vl.x);
                split_bf16(Yt[mi][half * 4 + 1][mm], vh.y, vl.y);
                split_bf16(Yt[mi][half * 4 + 2][mm], vh.z, vl.z);
                split_bf16(Yt[mi][half * 4 + 3][mm], vh.w, vl.w);
                const size_t eb = orow * D_IN + w64
                                + (size_t)((lc ^ (int)(orow & 7)) << 3) + half * 4;
                *reinterpret_cast<short4*>(&y2h[eb]) = vh;
                *reinterpret_cast<short4*>(&y2l[eb]) = vl;
            }
            __syncthreads();
        }
    }
}

extern "C" void kernel_launch(void* const* d_in, const int* in_sizes, int n_in,
                              void* d_out, int out_size, void* d_ws, size_t ws_size,
                              hipStream_t stream) {
    const float* x      = (const float*)d_in[0];
    const float* norm_w = (const float*)d_in[1];
    const float* Win    = (const float*)d_in[2];
    const float* b_in   = (const float*)d_in[3];
    const float* conv_w = (const float*)d_in[4];
    const float* conv_b = (const float*)d_in[5];
    const float* A      = (const float*)d_in[6];
    const float* Bm     = (const float*)d_in[7];
    const float* Cm     = (const float*)d_in[8];
    const float* Wout   = (const float*)d_in[9];
    const float* b_out  = (const float*)d_in[10];
    float* out = (float*)d_out;

    // ws (128MB), phase-overlapped:
    //   [0,64M):  u0T fp32 (gemm1 out; scan in)  -> later Woth@[0,4M), Wotl@[4,8M)
    //   [64,128M): Wth@[64,68M), Wtl@[68,72M)    -> later y2h@[64,96M), y2l@[96,128M)
    // d_out (32MB): hh/hl (rmsnorm->gemm1) -> mats (prep->scan) -> final output (gemm2)
    char* W = (char*)d_ws;
    float* u0T = (float*)W;
    u16* Wth  = (u16*)(W + ((size_t)64 << 20));
    u16* Wtl  = (u16*)(W + ((size_t)68 << 20));
    u16* y2h  = (u16*)(W + ((size_t)64 << 20));
    u16* y2l  = (u16*)(W + ((size_t)96 << 20));
    u16* Woth = (u16*)W;
    u16* Wotl = (u16*)(W + ((size_t)4 << 20));
    u16* hh = (u16*)d_out;
    u16* hl = hh + (size_t)NROWS * D_MODEL;
    float* mats = (float*)d_out;

    // 1) Win -> Win^T split/swizzled
    {
        dim3 g(D_IN / 64, D_MODEL / 64);
        transpose_cast_kernel<<<g, 256, 0, stream>>>(Win, Wth, Wtl, D_MODEL, D_IN);
    }
    // 2) RMSNorm -> h split/swizzled (d_out)
    rmsnorm_kernel<<<NROWS, 128, 0, stream>>>(x, norm_w, hh, hl);
    // 3) u0T = h @ Win + b_in
    {
        dim3 grid(D_IN / 128, NROWS / 128);
        gemm_gll<D_MODEL, 0><<<grid, 256, 0, stream>>>(Wth, Wtl, hh, hl, b_in, nullptr, u0T);
    }
    // 4) scan matrices -> mats (d_out; hh/hl dead)
    prep_kernel<<<D_IN, 256, 0, stream>>>(A, Bm, Cm, mats);
    // 5) conv+scan (DPP) -> y2 split/swizzled transposed [m][d] (Wt region dead)
    scan8_dpp<<<D_IN / 8, 512, 0, stream>>>(u0T, conv_w, conv_b, mats, y2h, y2l);
    // 6) Wout -> Wout^T split/swizzled (u0T dead)
    {
        dim3 g(D_MODEL / 64, D_IN / 64);
        transpose_cast_kernel<<<g, 256, 0, stream>>>(Wout, Woth, Wotl, D_IN, D_MODEL);
    }
    // 7) out = y @ Wout + b_out + x (mats dead)
    {
        dim3 grid(D_MODEL / 128, NROWS / 128);
        gemm_gll<D_IN, 1><<<grid, 256, 0, stream>>>(y2h, y2l, Woth, Wotl, b_out, x, out);
    }
}